// Round 9
// baseline (327.695 us; speedup 1.0000x reference)
//
#include <hip/hip_runtime.h>
#include <hip/hip_bf16.h>
#include <math.h>

#define DD 8192     // sketch dimension d
#define CC 768      // channels
#define SS 145      // sequence length
#define BB 32       // batch
#define SN 64       // sensor dim
#define SROWS 160   // padded s rows (10 tiles of 16)

// ---- kD geometry ----
#define TN 64            // e-cols per block
#define NET (CC/TN)      // 12 e-tiles
#define CK 64            // c per chunk
#define NCHK (CC/CK)     // 12 chunks
#define LTW 72           // Mt row stride in bf16 units (144 B, 16B-aligned)
#define NTD 512          // 8 waves
#define NWG (NET*BB*3)   // 1152 blocks

// ---- kZ geometry ----
#define ZT 512           // threads
#define NSL 16           // d-slices per b -> 512 blocks

typedef __attribute__((ext_vector_type(8))) short short8;   // 8 bf16 (4 VGPR)
typedef __attribute__((ext_vector_type(4))) float f32x4;    // MFMA acc

// ---------------------------------------------------------------------------
// kS: per-b sketch build (unchanged from R7). u[b,c]=b_sen[c]+sensor·Wsen[c,:];
// CTG[b][c]=(u1, s1, bits(h1c), 0); P2G[b][t]=(S2u_b[t], S2s[t]).
// ---------------------------------------------------------------------------
__global__ __launch_bounds__(512) void kS(
    const float* __restrict__ sensor, const float* __restrict__ Wsen,
    const float* __restrict__ bsen,
    const int* __restrict__ h1, const int* __restrict__ h2,
    const int* __restrict__ s1, const int* __restrict__ s2,
    float4* __restrict__ CTG, float2* __restrict__ P2G)
{
    __shared__ float2 P2l[DD];        // 64 KB
    __shared__ float  sens[SN];
    const int b   = blockIdx.x;
    const int tid = threadIdx.x;

    if (tid < SN) sens[tid] = sensor[b*SN + tid];
    {
        float4* p4 = (float4*)P2l;
        #pragma unroll
        for (int i = 0; i < 8; ++i) p4[tid + i*512] = make_float4(0.f,0.f,0.f,0.f);
    }
    __syncthreads();

    for (int c = tid; c < CC; c += 512) {
        float u = bsen[c];
        const float4* w = (const float4*)(Wsen + (size_t)c*SN);
        #pragma unroll
        for (int n4 = 0; n4 < 16; ++n4) {
            float4 wv = w[n4];
            u += sens[4*n4+0]*wv.x + sens[4*n4+1]*wv.y
               + sens[4*n4+2]*wv.z + sens[4*n4+3]*wv.w;
        }
        float f1 = (float)s1[c], f2 = (float)s2[c];
        float4 ct;
        ct.x = u * f1; ct.y = f1; ct.z = __int_as_float(h1[c]); ct.w = 0.f;
        CTG[(size_t)b*CC + c] = ct;
        int t = h2[c];
        unsafeAtomicAdd(&P2l[t].x, u * f2);
        unsafeAtomicAdd(&P2l[t].y, f2);
    }
    __syncthreads();

    {
        const float4* p4 = (const float4*)P2l;
        float4* dst = (float4*)(P2G + (size_t)b*DD);
        #pragma unroll
        for (int i = 0; i < 8; ++i) dst[tid + i*512] = p4[tid + i*512];
    }
}

// ---------------------------------------------------------------------------
// kZ: gather-free Z build via shifted-sketch sums (unchanged from R7).
//   Zuu_b[d]=sum_c u1[c]*S2u[(d-h1c)], Zcr_b[d]=sum u1*S2s+s1*S2u,
//   Z11[d]=sum s1*S2s (b==0 writes). Writes bf16 Zsb directly.
// ---------------------------------------------------------------------------
__global__ __launch_bounds__(ZT) void kZ(
    const float4* __restrict__ CTG, const float2* __restrict__ P2G,
    __hip_bfloat16* __restrict__ Zsb)
{
    __shared__ float2 P2l[DD];        // 64 KB -> 2 blocks/CU

    const int bid = blockIdx.x;
    const int wg  = (bid & 7)*(BB*NSL/8) + (bid >> 3);
    const int b   = wg >> 4;
    const int dsl = wg & (NSL-1);
    const int tid = threadIdx.x;

    {
        const float4* src = (const float4*)(P2G + (size_t)b*DD);
        float4* dst = (float4*)P2l;
        #pragma unroll
        for (int i = 0; i < 8; ++i) dst[tid + i*ZT] = src[tid + i*ZT];
    }
    __syncthreads();

    const int d = dsl*ZT + tid;
    const float4* ctp = CTG + (size_t)b*CC;
    float accU = 0.f, accC = 0.f, acc1 = 0.f;
    #pragma unroll 4
    for (int c = 0; c < CC; ++c) {
        float4 ct = ctp[c];                       // uniform -> s_load path
        int idx = (d - __float_as_int(ct.z)) & (DD-1);
        float2 p = P2l[idx];                      // conflict-free b64 gather
        accU = fmaf(ct.x, p.x, accU);
        accC = fmaf(ct.x, p.y, fmaf(ct.y, p.x, accC));
        acc1 = fmaf(ct.y, p.y, acc1);
    }

    Zsb[(size_t)b*DD + d]        = __float2bfloat16(accU);
    Zsb[(size_t)(BB + b)*DD + d] = __float2bfloat16(accC);
    if (b == 0) Zsb[(size_t)2*BB*DD + d] = __float2bfloat16(acc1);
}

// ---------------------------------------------------------------------------
// kA: precompute A1[b][sp][c] = bf16((E[b,sp,c]+tok1[c])*s1[c]), zero rows
// for sp>=SS. One write per element; 7.9 MB, L2-resident for kD.
// ---------------------------------------------------------------------------
__global__ __launch_bounds__(384) void kA(
    const float* __restrict__ E, const float* __restrict__ tok,
    const int* __restrict__ s1, __hip_bfloat16* __restrict__ A1)
{
    const int b  = blockIdx.x;
    const int r0 = blockIdx.y * 16;
    const int p  = threadIdx.x;           // c-pair 0..383
    const int c  = 2*p;
    const float s1a = (float)s1[c], s1b = (float)s1[c+1];
    const float ta = tok[CC + c] * s1a, tb = tok[CC + c + 1] * s1b;
    #pragma unroll
    for (int rr = 0; rr < 16; ++rr) {
        int sp = r0 + rr;
        unsigned int word = 0;
        if (sp < SS) {
            float2 ev = *(const float2*)&E[((size_t)b*SS + sp)*CC + c];
            __hip_bfloat16 x0 = __float2bfloat16(ev.x*s1a + ta);
            __hip_bfloat16 x1 = __float2bfloat16(ev.y*s1b + tb);
            word = (unsigned int)*(unsigned short*)&x0
                 | ((unsigned int)*(unsigned short*)&x1 << 16);
        }
        *(unsigned int*)&A1[((size_t)b*SROWS + sp)*CC + c] = word;
    }
}

// ---------------------------------------------------------------------------
// kD: bf16 MFMA quadratic forms, A-side direct from global.
// 1D grid, XCD-swizzled -> (b, m, et). Per block: stage Zm (16 KB bf16) +
// h tables; double-buffered Mt: per chunk, gather Mt[next] (LDS) while MFMA
// consumes Mt[cur] with A-fragments loaded straight from L2-hot A1 (16B
// aligned short8 per lane). ONE barrier per chunk. Epilogue contracts acc
// with a2 (fp32 from E), shfl-reduces over 16 e-lanes, scales by m-factor,
// atomicAdd into Q.  m=0: w2^2*Zuu[b]  m=1: w2*bb*Zcr[b]  m=2: bb^2*Z11.
// LDS 36.5 KB, launch_bounds(512,8) caps VGPR at 64 -> 4 blocks/CU = 32 waves.
// ---------------------------------------------------------------------------
__global__ __launch_bounds__(NTD, 8) void kD(
    const __hip_bfloat16* __restrict__ A1,
    const float* __restrict__ E, const float* __restrict__ tok,
    const int* __restrict__ h1, const int* __restrict__ h2,
    const int* __restrict__ s2,
    const float* __restrict__ Ws2, const float* __restrict__ bs2,
    const __hip_bfloat16* __restrict__ Zsb, float* __restrict__ Q)
{
    __shared__ __align__(16) unsigned short Zm[DD];        // 16384 B
    __shared__ __align__(16) unsigned short Mt[2][TN*LTW]; // 18432 B
    __shared__ unsigned short h1s[CC];                     //  1536 B
    __shared__ unsigned short h2s[TN];                     //   128 B

    const int bid = blockIdx.x;
    const int wg  = (bid & 7)*(NWG/8) + (bid >> 3);
    const int b   = wg / (3*NET);
    const int r   = wg % (3*NET);
    const int m   = r / NET;
    const int et  = r % NET;
    const int tid = threadIdx.x;
    const int e0  = et * TN;

    {
        const uint4* src = (const uint4*)(Zsb +
            (size_t)((m == 0) ? b : (m == 1) ? (BB + b) : 2*BB) * DD);
        uint4* dst = (uint4*)Zm;
        #pragma unroll
        for (int i = 0; i < 2; ++i) dst[tid + i*NTD] = src[tid + i*NTD];
    }
    for (int c = tid; c < CC; c += NTD) h1s[c] = (unsigned short)h1[c];
    if (tid < TN) h2s[tid] = (unsigned short)h2[e0 + tid];
    __syncthreads();

    const int lane = tid & 63;
    const int w    = tid >> 6;        // wave 0..7
    const int eT   = w & 3;           // e-tile within block
    const int sB   = (w >> 2) * 5;    // first s-tile
    const int l15  = lane & 15;
    const int l4   = lane >> 4;
    const int c2   = tid & 31;        // gather: c-pair
    const int eb   = tid >> 5;        // gather: e base

    // per-lane A1 base: row = b*160 + sB*16 + l15, k-offset l4*8
    const __hip_bfloat16* Abase =
        A1 + ((size_t)(b*SROWS + sB*16 + l15))*CC + l4*8;

#define GATHER(CKK, BUF) { \
    const int cbase = (CKK)*CK + 2*c2; \
    const int hA = (int)h1s[cbase], hB = (int)h1s[cbase + 1]; \
    _Pragma("unroll") \
    for (int j = 0; j < 4; ++j) { \
        int e  = eb + 16*j; \
        int he = (int)h2s[e]; \
        unsigned int lo = Zm[(hA + he) & (DD-1)]; \
        unsigned int hi = Zm[(hB + he) & (DD-1)]; \
        *(unsigned int*)&Mt[BUF][e*LTW + 2*c2] = lo | (hi << 16); \
    } }

    f32x4 acc[5];
    #pragma unroll
    for (int t = 0; t < 5; ++t) acc[t] = (f32x4){0.f, 0.f, 0.f, 0.f};

    GATHER(0, 0)
    __syncthreads();

    for (int ck = 0; ck < NCHK; ++ck) {
        const int cur = ck & 1;
        if (ck + 1 < NCHK) GATHER(ck + 1, cur ^ 1)   // overlaps MFMA below

        #pragma unroll 1
        for (int kk = 0; kk < 2; ++kk) {
            short8 bfrag = *(const short8*)&Mt[cur][(eT*16 + l15)*LTW
                                                    + kk*32 + l4*8];
            #pragma unroll
            for (int t = 0; t < 5; ++t) {
                short8 afrag = *(const short8*)&Abase[(size_t)t*16*CC
                                                       + ck*CK + kk*32];
                acc[t] = __builtin_amdgcn_mfma_f32_16x16x32_bf16(
                    afrag, bfrag, acc[t], 0, 0, 0);
            }
        }
        __syncthreads();
    }
#undef GATHER

    // --- epilogue: q[s] = sum_e acc * a2[s,e]; reduce 16 e-lanes; scale; add ---
    const int   eg  = e0 + eT*16 + l15;
    const float s2e = (float)s2[eg];
    const float t2e = tok[CC + eg] * s2e;
    #pragma unroll
    for (int t = 0; t < 5; ++t) {
        #pragma unroll
        for (int rr = 0; rr < 4; ++rr) {
            int s = (sB + t)*16 + l4*4 + rr;
            float qv = 0.f;
            if (s < SS) {
                float a2v = E[((size_t)b*SS + s)*CC + eg] * s2e + t2e;
                qv = acc[t][rr] * a2v;
            }
            qv += __shfl_xor(qv, 1);
            qv += __shfl_xor(qv, 2);
            qv += __shfl_xor(qv, 4);
            qv += __shfl_xor(qv, 8);
            if (l15 == 0 && s < SS) {
                float w2v = Ws2[s], bbv = bs2[s];
                float sc  = (m == 0) ? w2v*w2v : (m == 1) ? w2v*bbv : bbv*bbv;
                unsafeAtomicAdd(&Q[b*SS + s], sc * qv);
            }
        }
    }
}

// ---------------------------------------------------------------------------
// kE: bp = sign(Q)*sqrt(|Q|+1e-5); L2-normalize over s; project W_out.
// ---------------------------------------------------------------------------
__global__ __launch_bounds__(256) void kE(
    const float* __restrict__ Q, const float* __restrict__ Wout,
    const float* __restrict__ bout, float* __restrict__ out)
{
    __shared__ float red[8];
    const int b = blockIdx.x, tid = threadIdx.x;
    float v = 0.f, w = 0.f;
    if (tid < SS) {
        float ip = Q[b*SS + tid];
        float sg = (ip > 0.f) ? 1.f : ((ip < 0.f) ? -1.f : 0.f);
        v = sg * sqrtf(fabsf(ip) + 1e-5f);
        w = v * Wout[tid];
    }
    float sq = v * v;
    #pragma unroll
    for (int off = 32; off > 0; off >>= 1) {
        sq += __shfl_down(sq, off, 64);
        w  += __shfl_down(w,  off, 64);
    }
    if ((tid & 63) == 0) { red[tid >> 6] = sq; red[4 + (tid >> 6)] = w; }
    __syncthreads();
    if (tid == 0) {
        float ssq  = red[0] + red[1] + red[2] + red[3];
        float sw   = red[4] + red[5] + red[6] + red[7];
        float norm = fmaxf(sqrtf(ssq), 1e-12f);
        out[b] = sw / norm + bout[0];
    }
}

// ---------------------------------------------------------------------------
extern "C" void kernel_launch(void* const* d_in, const int* in_sizes, int n_in,
                              void* d_out, int out_size, void* d_ws, size_t ws_size,
                              hipStream_t stream) {
    const float* sensor = (const float*)d_in[0];
    const float* E      = (const float*)d_in[1];
    const int*   h1     = (const int*)d_in[3];
    const int*   h2     = (const int*)d_in[4];
    const int*   s1     = (const int*)d_in[5];
    const int*   s2     = (const int*)d_in[6];
    const float* Wsen   = (const float*)d_in[8];
    const float* bsen   = (const float*)d_in[9];
    const float* Ws2    = (const float*)d_in[10];
    const float* bs2    = (const float*)d_in[11];
    const float* Wout   = (const float*)d_in[12];
    const float* bout   = (const float*)d_in[13];
    const float* tok    = (const float*)d_in[14];
    float* out = (float*)d_out;

    // ws layout (~8.95 MB): A1 aliases the dead CTG+P2G region after kZ.
    //   [0 .. 7.86M)  phase1: CTG (0.39M) + P2G (2.1M)   phase2: A1 (7.86M)
    //   [7.86M ..)    Zsb (1.06M), then Q (18.5K)
    char* ws = (char*)d_ws;
    float4* CTG = (float4*)ws;
    float2* P2G = (float2*)(ws + (size_t)BB*CC*16);
    __hip_bfloat16* A1 = (__hip_bfloat16*)ws;
    const size_t A1_BYTES = (size_t)BB*SROWS*CC*2;            // 7,864,320
    __hip_bfloat16* Zsb = (__hip_bfloat16*)(ws + A1_BYTES);
    float* Q = (float*)(ws + A1_BYTES + (size_t)(2*BB+1)*DD*2);

    hipMemsetAsync(Q, 0, (size_t)BB*SS*sizeof(float), stream);

    kS<<<dim3(BB), dim3(512), 0, stream>>>(
        sensor, Wsen, bsen, h1, h2, s1, s2, CTG, P2G);

    kZ<<<dim3(BB*NSL), dim3(ZT), 0, stream>>>(CTG, P2G, Zsb);

    // kA overwrites CTG/P2G (same stream => ordered after kZ)
    kA<<<dim3(BB, SROWS/16), dim3(384), 0, stream>>>(E, tok, s1, A1);

    kD<<<dim3(NWG), dim3(NTD), 0, stream>>>(
        A1, E, tok, h1, h2, s2, Ws2, bs2, Zsb, Q);

    kE<<<dim3(BB), dim3(256), 0, stream>>>(Q, Wout, bout, out);
}

// Round 10
// 257.200 us; speedup vs baseline: 1.2741x; 1.2741x over previous
//
#include <hip/hip_runtime.h>
#include <hip/hip_bf16.h>
#include <math.h>

#define DD 8192     // sketch dimension d
#define CC 768      // channels
#define SS 145      // sequence length
#define BB 32       // batch
#define SN 64       // sensor dim
#define SROWS 160   // padded s rows (10 tiles of 16)

// ---- kD geometry ----
#define TN 64            // e-cols per block
#define NET (CC/TN)      // 12 e-tiles
#define CK2 128          // c per chunk
#define NCHK2 (CC/CK2)   // 6 chunks
#define LTW2 136         // Lt/Mt row stride in bf16 units (272 B, 16B-aligned)
#define NTD 512          // 8 waves
#define NWG (NET*BB*3)   // 1152 blocks

// ---- kZ geometry ----
#define ZT 512           // threads
#define NSL 16           // d-slices per b -> 512 blocks

typedef __attribute__((ext_vector_type(8))) short short8;   // 8 bf16 (4 VGPR)
typedef __attribute__((ext_vector_type(4))) float f32x4;    // MFMA acc

// ---------------------------------------------------------------------------
// kS: per-b sketch build. u[b,c]=b_sen[c]+sensor·Wsen[c,:];
// CTG[b][c]=(u1, s1, bits(h1c), 0); P2G[b][t]=(S2u_b[t], S2s[t]).
// ---------------------------------------------------------------------------
__global__ __launch_bounds__(512) void kS(
    const float* __restrict__ sensor, const float* __restrict__ Wsen,
    const float* __restrict__ bsen,
    const int* __restrict__ h1, const int* __restrict__ h2,
    const int* __restrict__ s1, const int* __restrict__ s2,
    float4* __restrict__ CTG, float2* __restrict__ P2G)
{
    __shared__ float2 P2l[DD];        // 64 KB
    __shared__ float  sens[SN];
    const int b   = blockIdx.x;
    const int tid = threadIdx.x;

    if (tid < SN) sens[tid] = sensor[b*SN + tid];
    {
        float4* p4 = (float4*)P2l;
        #pragma unroll
        for (int i = 0; i < 8; ++i) p4[tid + i*512] = make_float4(0.f,0.f,0.f,0.f);
    }
    __syncthreads();

    for (int c = tid; c < CC; c += 512) {
        float u = bsen[c];
        const float4* w = (const float4*)(Wsen + (size_t)c*SN);
        #pragma unroll
        for (int n4 = 0; n4 < 16; ++n4) {
            float4 wv = w[n4];
            u += sens[4*n4+0]*wv.x + sens[4*n4+1]*wv.y
               + sens[4*n4+2]*wv.z + sens[4*n4+3]*wv.w;
        }
        float f1 = (float)s1[c], f2 = (float)s2[c];
        float4 ct;
        ct.x = u * f1; ct.y = f1; ct.z = __int_as_float(h1[c]); ct.w = 0.f;
        CTG[(size_t)b*CC + c] = ct;
        int t = h2[c];
        unsafeAtomicAdd(&P2l[t].x, u * f2);
        unsafeAtomicAdd(&P2l[t].y, f2);
    }
    __syncthreads();

    {
        const float4* p4 = (const float4*)P2l;
        float4* dst = (float4*)(P2G + (size_t)b*DD);
        #pragma unroll
        for (int i = 0; i < 8; ++i) dst[tid + i*512] = p4[tid + i*512];
    }
}

// ---------------------------------------------------------------------------
// kZ: gather-free Z build via shifted-sketch sums (unchanged).
//   Zuu_b[d]=sum_c u1[c]*S2u[(d-h1c)], Zcr_b[d]=sum u1*S2s+s1*S2u,
//   Z11[d]=sum s1*S2s (b==0 writes). Writes bf16 Zsb directly.
// ---------------------------------------------------------------------------
__global__ __launch_bounds__(ZT) void kZ(
    const float4* __restrict__ CTG, const float2* __restrict__ P2G,
    __hip_bfloat16* __restrict__ Zsb)
{
    __shared__ float2 P2l[DD];        // 64 KB -> 2 blocks/CU

    const int bid = blockIdx.x;
    const int wg  = (bid & 7)*(BB*NSL/8) + (bid >> 3);
    const int b   = wg >> 4;
    const int dsl = wg & (NSL-1);
    const int tid = threadIdx.x;

    {
        const float4* src = (const float4*)(P2G + (size_t)b*DD);
        float4* dst = (float4*)P2l;
        #pragma unroll
        for (int i = 0; i < 8; ++i) dst[tid + i*ZT] = src[tid + i*ZT];
    }
    __syncthreads();

    const int d = dsl*ZT + tid;
    const float4* ctp = CTG + (size_t)b*CC;
    float accU = 0.f, accC = 0.f, acc1 = 0.f;
    #pragma unroll 4
    for (int c = 0; c < CC; ++c) {
        float4 ct = ctp[c];                       // uniform -> s_load path
        int idx = (d - __float_as_int(ct.z)) & (DD-1);
        float2 p = P2l[idx];                      // conflict-free b64 gather
        accU = fmaf(ct.x, p.x, accU);
        accC = fmaf(ct.x, p.y, fmaf(ct.y, p.x, accC));
        acc1 = fmaf(ct.y, p.y, acc1);
    }

    Zsb[(size_t)b*DD + d]        = __float2bfloat16(accU);
    Zsb[(size_t)(BB + b)*DD + d] = __float2bfloat16(accC);
    if (b == 0) Zsb[(size_t)2*BB*DD + d] = __float2bfloat16(acc1);
}

// ---------------------------------------------------------------------------
// kA: precompute A1[b][sp][c] = bf16((E[b,sp,c]+tok1[c])*s1[c]), zero rows
// for sp>=SS. 7.9 MB, L2-resident for kD.
// ---------------------------------------------------------------------------
__global__ __launch_bounds__(384) void kA(
    const float* __restrict__ E, const float* __restrict__ tok,
    const int* __restrict__ s1, __hip_bfloat16* __restrict__ A1)
{
    const int b  = blockIdx.x;
    const int r0 = blockIdx.y * 16;
    const int p  = threadIdx.x;           // c-pair 0..383
    const int c  = 2*p;
    const float s1a = (float)s1[c], s1b = (float)s1[c+1];
    const float ta = tok[CC + c] * s1a, tb = tok[CC + c + 1] * s1b;
    #pragma unroll
    for (int rr = 0; rr < 16; ++rr) {
        int sp = r0 + rr;
        unsigned int word = 0;
        if (sp < SS) {
            float2 ev = *(const float2*)&E[((size_t)b*SS + sp)*CC + c];
            __hip_bfloat16 x0 = __float2bfloat16(ev.x*s1a + ta);
            __hip_bfloat16 x1 = __float2bfloat16(ev.y*s1b + tb);
            word = (unsigned int)*(unsigned short*)&x0
                 | ((unsigned int)*(unsigned short*)&x1 << 16);
        }
        *(unsigned int*)&A1[((size_t)b*SROWS + sp)*CC + c] = word;
    }
}

// ---------------------------------------------------------------------------
// kD: bf16 MFMA quadratic forms. A-panel staged into LDS from bf16 A1 as
// pure uint4 copies (coalesced 256B per 16 lanes, no cvt), with T14 split:
// chunk k+1's 5 loads issue BEFORE chunk k's MFMA loop and land in LDS
// after the post-MFMA barrier. CK=128 -> 6 chunks, 2 barriers each.
// Mt gathered from Zm (LDS-only). MFMA: wave w: e-tile (w&3), 5 s-tiles
// ((w>>2)*5..). Epilogue contracts acc with a2 (fp32 E), shfl-reduce over
// 16 e-lanes, scale by m-factor, atomicAdd into Q.
//   m=0: w2^2*Zuu[b]  m=1: w2*bb*Zcr[b]  m=2: bb^2*Z11.
// LDS 78.9 KB -> 2 blocks/CU (16 waves). launch_bounds(512,4): VGPR cap 128.
// ---------------------------------------------------------------------------
__global__ __launch_bounds__(NTD, 4) void kD(
    const __hip_bfloat16* __restrict__ A1,
    const float* __restrict__ E, const float* __restrict__ tok,
    const int* __restrict__ h1, const int* __restrict__ h2,
    const int* __restrict__ s2,
    const float* __restrict__ Ws2, const float* __restrict__ bs2,
    const __hip_bfloat16* __restrict__ Zsb, float* __restrict__ Q)
{
    __shared__ __align__(16) unsigned short Zm[DD];           // 16384 B
    __shared__ __align__(16) unsigned short Lt[SROWS*LTW2];   // 43520 B
    __shared__ __align__(16) unsigned short Mt[TN*LTW2];      // 17408 B
    __shared__ unsigned short h1s[CC];                        //  1536 B
    __shared__ unsigned short h2s[TN];                        //   128 B
    // total 78976 B -> 2 blocks/CU

    const int bid = blockIdx.x;
    const int wg  = (bid & 7)*(NWG/8) + (bid >> 3);
    const int b   = wg / (3*NET);
    const int r   = wg % (3*NET);
    const int m   = r / NET;
    const int et  = r % NET;
    const int tid = threadIdx.x;
    const int e0  = et * TN;

    {
        const uint4* src = (const uint4*)(Zsb +
            (size_t)((m == 0) ? b : (m == 1) ? (BB + b) : 2*BB) * DD);
        uint4* dst = (uint4*)Zm;
        #pragma unroll
        for (int i = 0; i < 2; ++i) dst[tid + i*NTD] = src[tid + i*NTD];
    }
    for (int c = tid; c < CC; c += NTD) h1s[c] = (unsigned short)h1[c];
    if (tid < TN) h2s[tid] = (unsigned short)h2[e0 + tid];
    __syncthreads();

    const int lane = tid & 63;
    const int w    = tid >> 6;        // wave 0..7
    const int eT   = w & 3;           // e-tile within block
    const int sB   = (w >> 2) * 5;    // first s-tile
    const int l15  = lane & 15;
    const int l4   = lane >> 4;

    // staging maps: Lt copy (2560 uint4 = 512 thr x 5), Mt gather
    const int rA = tid >> 4;          // base row (tid/16), +32 per k
    const int qA = tid & 15;          // uint4 col within row
    const int c2g = tid & 63;         // gather: u32 col (c-pair)
    const int ebg = tid >> 6;         // gather: e base (0..7)
    const __hip_bfloat16* Arow = A1 + (size_t)b*SROWS*CC + qA*8;

    uint4 pf[5];
#define PRELOAD(CKK) { \
    _Pragma("unroll") \
    for (int k = 0; k < 5; ++k) \
        pf[k] = *(const uint4*)&Arow[(size_t)(rA + 32*k)*CC + (CKK)*CK2]; \
    }
#define WRITE_A { \
    _Pragma("unroll") \
    for (int k = 0; k < 5; ++k) \
        *(uint4*)&Lt[(rA + 32*k)*LTW2 + qA*8] = pf[k]; \
    }
#define GATHER(CKK) { \
    const int cbase = (CKK)*CK2 + 2*c2g; \
    const int hA = (int)h1s[cbase], hB = (int)h1s[cbase + 1]; \
    _Pragma("unroll") \
    for (int j = 0; j < 8; ++j) { \
        int e  = ebg + 8*j; \
        int he = (int)h2s[e]; \
        unsigned int lo = Zm[(hA + he) & (DD-1)]; \
        unsigned int hi = Zm[(hB + he) & (DD-1)]; \
        *(unsigned int*)&Mt[e*LTW2 + 2*c2g] = lo | (hi << 16); \
    } }

    f32x4 acc[5];
    #pragma unroll
    for (int t = 0; t < 5; ++t) acc[t] = (f32x4){0.f, 0.f, 0.f, 0.f};

    PRELOAD(0)
    WRITE_A
    GATHER(0)
    __syncthreads();

    for (int ck = 0; ck < NCHK2; ++ck) {
        if (ck + 1 < NCHK2) PRELOAD(ck + 1)    // latency hides under MFMA+bar

        #pragma unroll
        for (int kk = 0; kk < 4; ++kk) {
            const int kb = kk*32 + l4*8;
            short8 bfrag = *(const short8*)&Mt[(eT*16 + l15)*LTW2 + kb];
            #pragma unroll
            for (int t = 0; t < 5; ++t) {
                short8 afrag = *(const short8*)&Lt[((sB + t)*16 + l15)*LTW2 + kb];
                acc[t] = __builtin_amdgcn_mfma_f32_16x16x32_bf16(
                    afrag, bfrag, acc[t], 0, 0, 0);
            }
        }
        __syncthreads();

        if (ck + 1 < NCHK2) {
            WRITE_A
            GATHER(ck + 1)
            __syncthreads();
        }
    }
#undef PRELOAD
#undef WRITE_A
#undef GATHER

    // --- epilogue: q[s] = sum_e acc * a2[s,e]; reduce 16 e-lanes; scale; add ---
    const int   eg  = e0 + eT*16 + l15;
    const float s2e = (float)s2[eg];
    const float t2e = tok[CC + eg] * s2e;
    #pragma unroll
    for (int t = 0; t < 5; ++t) {
        #pragma unroll
        for (int rr = 0; rr < 4; ++rr) {
            int s = (sB + t)*16 + l4*4 + rr;
            float qv = 0.f;
            if (s < SS) {
                float a2v = E[((size_t)b*SS + s)*CC + eg] * s2e + t2e;
                qv = acc[t][rr] * a2v;
            }
            qv += __shfl_xor(qv, 1);
            qv += __shfl_xor(qv, 2);
            qv += __shfl_xor(qv, 4);
            qv += __shfl_xor(qv, 8);
            if (l15 == 0 && s < SS) {
                float w2v = Ws2[s], bbv = bs2[s];
                float sc  = (m == 0) ? w2v*w2v : (m == 1) ? w2v*bbv : bbv*bbv;
                unsafeAtomicAdd(&Q[b*SS + s], sc * qv);
            }
        }
    }
}

// ---------------------------------------------------------------------------
// kE: bp = sign(Q)*sqrt(|Q|+1e-5); L2-normalize over s; project W_out.
// ---------------------------------------------------------------------------
__global__ __launch_bounds__(256) void kE(
    const float* __restrict__ Q, const float* __restrict__ Wout,
    const float* __restrict__ bout, float* __restrict__ out)
{
    __shared__ float red[8];
    const int b = blockIdx.x, tid = threadIdx.x;
    float v = 0.f, w = 0.f;
    if (tid < SS) {
        float ip = Q[b*SS + tid];
        float sg = (ip > 0.f) ? 1.f : ((ip < 0.f) ? -1.f : 0.f);
        v = sg * sqrtf(fabsf(ip) + 1e-5f);
        w = v * Wout[tid];
    }
    float sq = v * v;
    #pragma unroll
    for (int off = 32; off > 0; off >>= 1) {
        sq += __shfl_down(sq, off, 64);
        w  += __shfl_down(w,  off, 64);
    }
    if ((tid & 63) == 0) { red[tid >> 6] = sq; red[4 + (tid >> 6)] = w; }
    __syncthreads();
    if (tid == 0) {
        float ssq  = red[0] + red[1] + red[2] + red[3];
        float sw   = red[4] + red[5] + red[6] + red[7];
        float norm = fmaxf(sqrtf(ssq), 1e-12f);
        out[b] = sw / norm + bout[0];
    }
}

// ---------------------------------------------------------------------------
extern "C" void kernel_launch(void* const* d_in, const int* in_sizes, int n_in,
                              void* d_out, int out_size, void* d_ws, size_t ws_size,
                              hipStream_t stream) {
    const float* sensor = (const float*)d_in[0];
    const float* E      = (const float*)d_in[1];
    const int*   h1     = (const int*)d_in[3];
    const int*   h2     = (const int*)d_in[4];
    const int*   s1     = (const int*)d_in[5];
    const int*   s2     = (const int*)d_in[6];
    const float* Wsen   = (const float*)d_in[8];
    const float* bsen   = (const float*)d_in[9];
    const float* Ws2    = (const float*)d_in[10];
    const float* bs2    = (const float*)d_in[11];
    const float* Wout   = (const float*)d_in[12];
    const float* bout   = (const float*)d_in[13];
    const float* tok    = (const float*)d_in[14];
    float* out = (float*)d_out;

    // ws layout (~8.95 MB): A1 aliases dead CTG+P2G region after kZ.
    char* ws = (char*)d_ws;
    float4* CTG = (float4*)ws;
    float2* P2G = (float2*)(ws + (size_t)BB*CC*16);
    __hip_bfloat16* A1 = (__hip_bfloat16*)ws;
    const size_t A1_BYTES = (size_t)BB*SROWS*CC*2;            // 7,864,320
    __hip_bfloat16* Zsb = (__hip_bfloat16*)(ws + A1_BYTES);
    float* Q = (float*)(ws + A1_BYTES + (size_t)(2*BB+1)*DD*2);

    hipMemsetAsync(Q, 0, (size_t)BB*SS*sizeof(float), stream);

    kS<<<dim3(BB), dim3(512), 0, stream>>>(
        sensor, Wsen, bsen, h1, h2, s1, s2, CTG, P2G);

    kZ<<<dim3(BB*NSL), dim3(ZT), 0, stream>>>(CTG, P2G, Zsb);

    // kA overwrites CTG/P2G (same stream => ordered after kZ)
    kA<<<dim3(BB, SROWS/16), dim3(384), 0, stream>>>(E, tok, s1, A1);

    kD<<<dim3(NWG), dim3(NTD), 0, stream>>>(
        A1, E, tok, h1, h2, s2, Ws2, bs2, Zsb, Q);

    kE<<<dim3(BB), dim3(256), 0, stream>>>(Q, Wout, bout, out);
}